// Round 3
// baseline (137.321 us; speedup 1.0000x reference)
//
#include <hip/hip_runtime.h>

#define NN 50000
#define NE 640000
#define DIM 128
#define NCHUNK 49   // ceil(NN/1024)

// ---------------- kernel 1: gate scores + out x-half + zero counts ----------------
__global__ void k_gate(const float* __restrict__ x,
                       const float* __restrict__ gw,
                       const float* __restrict__ gb,
                       float* __restrict__ out,
                       float* __restrict__ gate,
                       int* __restrict__ cnt) {
    int wid = (blockIdx.x * blockDim.x + threadIdx.x) >> 6;
    int lane = threadIdx.x & 63;
    if (wid >= NN) return;
    const float2* xr = (const float2*)(x + (size_t)wid * DIM);
    const float2* wr = (const float2*)gw;
    float2 xv = xr[lane];
    float2 wv = wr[lane];
    float p = xv.x * wv.x + xv.y * wv.y;
    #pragma unroll
    for (int off = 32; off; off >>= 1) p += __shfl_xor(p, off);
    float2* o = (float2*)(out + (size_t)wid * (2 * DIM));
    o[lane] = xv;
    if (lane == 0) {
        gate[wid] = p + gb[0];
        cnt[wid] = 0;
    }
}

// ---------------- kernel 2: degree histogram ----------------
__global__ void k_count(const int* __restrict__ dst, int* __restrict__ cnt) {
    int e = blockIdx.x * blockDim.x + threadIdx.x;
    if (e >= NE) return;
    atomicAdd(&cnt[dst[e]], 1);
}

// ---------------- scan (3 kernels) ----------------
__global__ void k_scan_a(const int* __restrict__ cnt, int* __restrict__ off,
                         int* __restrict__ bsum) {
    __shared__ int wsum[16];
    int tid = threadIdx.x;
    int i = blockIdx.x * 1024 + tid;
    int v = (i < NN) ? cnt[i] : 0;
    int incl = v;
    #pragma unroll
    for (int s = 1; s < 64; s <<= 1) {
        int t = __shfl_up(incl, s);
        if ((tid & 63) >= s) incl += t;
    }
    int wave = tid >> 6;
    if ((tid & 63) == 63) wsum[wave] = incl;
    __syncthreads();
    if (tid < 16) {
        int t = wsum[tid];
        #pragma unroll
        for (int s = 1; s < 16; s <<= 1) {
            int u = __shfl_up(t, s);
            if (tid >= s) t += u;
        }
        wsum[tid] = t;
    }
    __syncthreads();
    int waveoff = wave ? wsum[wave - 1] : 0;
    incl += waveoff;
    if (i < NN) off[i] = incl - v;   // chunk-local exclusive
    if (tid == 1023) bsum[blockIdx.x] = incl;
}

__global__ void k_scan_b(const int* __restrict__ bsum, int* __restrict__ boff) {
    int tid = threadIdx.x;  // 64
    int v = (tid < NCHUNK) ? bsum[tid] : 0;
    int incl = v;
    #pragma unroll
    for (int s = 1; s < 64; s <<= 1) {
        int t = __shfl_up(incl, s);
        if (tid >= s) incl += t;
    }
    if (tid < NCHUNK) boff[tid] = incl - v;
}

__global__ void k_scan_c(int* __restrict__ off, const int* __restrict__ boff,
                         int* __restrict__ cur) {
    int i = blockIdx.x * 1024 + threadIdx.x;
    if (i < NN) {
        int val = off[i] + boff[blockIdx.x];
        off[i] = val;
        cur[i] = val;
    }
    if (i == 0) off[NN] = NE;
}

// ---------------- kernel 4: scatter edges into CSR order (packed 8B) ----------------
__global__ void k_scatter(const int* __restrict__ src, const int* __restrict__ dst,
                          const float* __restrict__ gate,
                          int* __restrict__ cur,
                          int2* __restrict__ epack) {
    int e = blockIdx.x * blockDim.x + threadIdx.x;
    if (e >= NE) return;
    int s = src[e];
    int d = dst[e];
    int pos = atomicAdd(&cur[d], 1);
    int2 p;
    p.x = s;
    p.y = __float_as_int(gate[s]);
    epack[pos] = p;   // single 8B store: one dirty line per edge
}

// ---------------- kernel 5: per-node softmax-weighted aggregation ----------------
__global__ void k_node_agg(const int* __restrict__ off,
                           const int2* __restrict__ epack,
                           const float* __restrict__ x,
                           float* __restrict__ out) {
    int wid = (blockIdx.x * blockDim.x + threadIdx.x) >> 6;
    int lane = threadIdx.x & 63;
    if (wid >= NN) return;
    int b = off[wid];
    int e = off[wid + 1];

    // pass A: max and denom, edges distributed across lanes (coalesced epack reads)
    float m = -INFINITY;
    for (int j = b + lane; j < e; j += 64) m = fmaxf(m, __int_as_float(epack[j].y));
    #pragma unroll
    for (int o_ = 32; o_; o_ >>= 1) m = fmaxf(m, __shfl_xor(m, o_));
    float dsum = 0.f;
    for (int j = b + lane; j < e; j += 64) dsum += __expf(__int_as_float(epack[j].y) - m);
    #pragma unroll
    for (int o_ = 32; o_; o_ >>= 1) dsum += __shfl_xor(dsum, o_);
    float inv = 1.0f / fmaxf(dsum, 1e-16f);

    // pass B: quarter-wave (16 lanes) per edge -> 4 edges + 8 x-loads in flight
    int g  = lane >> 4;   // group 0..3
    int gl = lane & 15;   // lane within group; covers dims [4gl..4gl+3] and [4(gl+16)..]
    float4 a0 = make_float4(0.f, 0.f, 0.f, 0.f);
    float4 a1 = make_float4(0.f, 0.f, 0.f, 0.f);
    #pragma unroll 2
    for (int j = b + g; j < e; j += 4) {
        int2 p = epack[j];
        float w = __expf(__int_as_float(p.y) - m) * inv;
        const float4* xs = (const float4*)(x + (size_t)p.x * DIM);
        float4 v0 = xs[gl];
        float4 v1 = xs[gl + 16];
        a0.x += w * v0.x; a0.y += w * v0.y; a0.z += w * v0.z; a0.w += w * v0.w;
        a1.x += w * v1.x; a1.y += w * v1.y; a1.z += w * v1.z; a1.w += w * v1.w;
    }
    // butterfly combine across the 4 groups (xor 16, then 32)
    #pragma unroll
    for (int s_ = 16; s_ <= 32; s_ <<= 1) {
        a0.x += __shfl_xor(a0.x, s_); a0.y += __shfl_xor(a0.y, s_);
        a0.z += __shfl_xor(a0.z, s_); a0.w += __shfl_xor(a0.w, s_);
        a1.x += __shfl_xor(a1.x, s_); a1.y += __shfl_xor(a1.y, s_);
        a1.z += __shfl_xor(a1.z, s_); a1.w += __shfl_xor(a1.w, s_);
    }
    float* o = out + (size_t)wid * (2 * DIM) + DIM;
    if (g == 0) {
        ((float4*)o)[gl] = a0;
        ((float4*)o)[gl + 16] = a1;
    }
}

extern "C" void kernel_launch(void* const* d_in, const int* in_sizes, int n_in,
                              void* d_out, int out_size, void* d_ws, size_t ws_size,
                              hipStream_t stream) {
    const float* x  = (const float*)d_in[0];
    const float* gw = (const float*)d_in[1];
    const float* gb = (const float*)d_in[2];
    const int* ei   = (const int*)d_in[3];
    const int* src  = ei;           // edge_index[0]
    const int* dst  = ei + NE;      // edge_index[1]
    float* out = (float*)d_out;

    // workspace layout (keep epack 8B-aligned: pad off to NN+2)
    float* gate   = (float*)d_ws;            // NN
    int*   cnt    = (int*)(gate + NN);       // NN
    int*   off    = cnt + NN;                // NN+2 (padded)
    int*   cur    = off + NN + 2;            // NN
    int*   bsum   = cur + NN;                // 64
    int*   boff   = bsum + 64;               // 64
    int2*  epack  = (int2*)(boff + 64);      // NE

    k_gate<<<(NN * 64 + 255) / 256, 256, 0, stream>>>(x, gw, gb, out, gate, cnt);
    k_count<<<(NE + 255) / 256, 256, 0, stream>>>(dst, cnt);
    k_scan_a<<<NCHUNK, 1024, 0, stream>>>(cnt, off, bsum);
    k_scan_b<<<1, 64, 0, stream>>>(bsum, boff);
    k_scan_c<<<NCHUNK, 1024, 0, stream>>>(off, boff, cur);
    k_scatter<<<(NE + 255) / 256, 256, 0, stream>>>(src, dst, gate, cur, epack);
    k_node_agg<<<(NN * 64 + 255) / 256, 256, 0, stream>>>(off, epack, x, out);
}